// Round 10
// baseline (293.800 us; speedup 1.0000x reference)
//
#include <hip/hip_runtime.h>
#include <hip/hip_bf16.h>
#include <math.h>

#define BB 2
#define CC 256
#define NN 6272      // 8*28*28
#define NT16 392     // 16-query tiles per batch
#define NKB32 196    // 32-key tiles per batch
#define SCL 0.09016844005f   // log2(e)/sqrt(256)  (folded into Q at projection)

typedef __attribute__((ext_vector_type(8))) short s8v;   // 8 bf16 (4 VGPRs)
typedef __attribute__((ext_vector_type(4))) float f4v;   // MFMA acc / 16B vec
typedef __attribute__((ext_vector_type(4))) unsigned short us4v;  // 4 bf16

__device__ inline unsigned short f2bf(float f) {
  unsigned u = __builtin_bit_cast(unsigned, f);
  u += 0x7fffu + ((u >> 16) & 1u);     // RNE
  return (unsigned short)(u >> 16);
}

__device__ inline float bf2f(unsigned short h) {
  unsigned u = (unsigned)h << 16;
  return __builtin_bit_cast(float, u);
}

// ---------------------------------------------------------------------------
// fp32 weights -> bf16 (once per launch)
// ---------------------------------------------------------------------------
__global__ __launch_bounds__(256) void wcvt_kernel(
    const float* __restrict__ wq, const float* __restrict__ wk,
    const float* __restrict__ wv, unsigned short* __restrict__ Wb)
{
  int i = (blockIdx.x * 256 + threadIdx.x) * 4;   // grid 192 -> i < 196608
  const float* src = (i < 65536) ? wq : (i < 131072 ? wk : wv);
  int off = i & 65535;
  float4 v = *(const float4*)(src + off);
  ushort4 o;
  o.x = f2bf(v.x); o.y = f2bf(v.y); o.z = f2bf(v.z); o.w = f2bf(v.w);
  *(ushort4*)(Wb + i) = o;
}

// ---------------------------------------------------------------------------
// MFMA projection
// p=0: Q*SCL -> [B][N][C]   p=1: K -> [B][N][C]   p=2: V -> [B][C][N]
// ---------------------------------------------------------------------------
__global__ __launch_bounds__(256) void proj_kernel(
    const float* __restrict__ x, const float* __restrict__ ctx,
    const unsigned short* __restrict__ Wb,
    const float* __restrict__ bq, const float* __restrict__ bk,
    const float* __restrict__ bv,
    unsigned short* __restrict__ Q, unsigned short* __restrict__ Kk,
    unsigned short* __restrict__ V)
{
  const int p = blockIdx.z, b = blockIdx.y;
  const int n0 = blockIdx.x * 32;
  const int tid = threadIdx.x;
  const float* in = (p == 0 ? x : ctx) + (size_t)b * CC * NN;
  const unsigned short* W = Wb + (size_t)p * 65536;
  const float* bias = (p == 0 ? bq : (p == 1 ? bk : bv));

  __shared__ __align__(16) unsigned short lds[32][264];   // [n][c]
  for (int it = tid; it < 2048; it += 256) {
    int c  = it >> 3;
    int n4 = (it & 7) << 2;
    float4 v = *(const float4*)(in + (size_t)c * NN + n0 + n4);
    lds[n4 + 0][c] = f2bf(v.x);
    lds[n4 + 1][c] = f2bf(v.y);
    lds[n4 + 2][c] = f2bf(v.z);
    lds[n4 + 3][c] = f2bf(v.w);
  }
  __syncthreads();

  const int lane = tid & 63, l15 = lane & 15, g = lane >> 4;
  const int obase = (tid >> 6) * 64;

  f4v acc[4][2];
#pragma unroll
  for (int mt = 0; mt < 4; ++mt) {
    float4 b4 = *(const float4*)(bias + obase + mt * 16 + g * 4);
    f4v bi = {b4.x, b4.y, b4.z, b4.w};
    acc[mt][0] = bi; acc[mt][1] = bi;
  }

#pragma unroll
  for (int ks = 0; ks < 8; ++ks) {
    s8v bf0 = *(const s8v*)(&lds[l15][ks * 32 + g * 8]);
    s8v bf1 = *(const s8v*)(&lds[16 + l15][ks * 32 + g * 8]);
#pragma unroll
    for (int mt = 0; mt < 4; ++mt) {
      s8v wa = *(const s8v*)(W + (size_t)(obase + mt * 16 + l15) * CC + ks * 32 + g * 8);
      acc[mt][0] = __builtin_amdgcn_mfma_f32_16x16x32_bf16(wa, bf0, acc[mt][0], 0, 0, 0);
      acc[mt][1] = __builtin_amdgcn_mfma_f32_16x16x32_bf16(wa, bf1, acc[mt][1], 0, 0, 0);
    }
  }

  if (p == 0) {
#pragma unroll
    for (int mt = 0; mt < 4; ++mt)
#pragma unroll
      for (int qq = 0; qq < 2; ++qq)
#pragma unroll
        for (int r = 0; r < 4; ++r)
          acc[mt][qq][r] *= SCL;
  }

  if (p < 2) {
    unsigned short* dst = (p == 0 ? Q : Kk) + (size_t)b * NN * CC;
#pragma unroll
    for (int mt = 0; mt < 4; ++mt)
#pragma unroll
      for (int qq = 0; qq < 2; ++qq) {
        ushort4 pk;
        pk.x = f2bf(acc[mt][qq][0]); pk.y = f2bf(acc[mt][qq][1]);
        pk.z = f2bf(acc[mt][qq][2]); pk.w = f2bf(acc[mt][qq][3]);
        *(ushort4*)(dst + (size_t)(n0 + qq * 16 + l15) * CC + obase + mt * 16 + g * 4) = pk;
      }
  } else {
    unsigned short* dstb = V + (size_t)b * CC * NN;
#pragma unroll
    for (int mt = 0; mt < 4; ++mt)
#pragma unroll
      for (int qq = 0; qq < 2; ++qq)
#pragma unroll
        for (int r = 0; r < 4; ++r)
          dstb[(size_t)(obase + mt * 16 + g * 4 + r) * NN + n0 + qq * 16 + l15] =
              f2bf(acc[mt][qq][r]);
  }
}

// ---------------------------------------------------------------------------
// Flash attention (no-max exp2). 512-thread blocks = 8 waves, 16 queries/wave.
// Contiguous split-K (split=5 -> 490 blocks = one full resident round).
// K/V double-buffered in LDS via global_load_lds (16B chunks), global-side
// XOR swizzles keep all fragment ds_read_b128 conflict-free.
// Partials stored bf16 fragment-native (halves merge HBM traffic).
// ---------------------------------------------------------------------------
__global__ __launch_bounds__(512, 4) void attn_kernel(
    const unsigned short* __restrict__ Qg,
    const unsigned short* __restrict__ Kg,
    const unsigned short* __restrict__ Vg,
    unsigned short* __restrict__ Opart,  // [wid16*split+s][4096] bf16
    float* __restrict__ ml,              // [wid16*split+s][16]
    int split, int kb_base, int kb_rem)
{
  const int s     = blockIdx.x % split;
  const int stile = blockIdx.x / split;   // 0..97
  const int b     = stile / 49;
  const int qsup  = stile % 49;
  const int tid   = threadIdx.x;
  const int w     = tid >> 6;             // 0..7
  const int lane  = tid & 63;
  const int l15 = lane & 15, g = lane >> 4;
  const int qt16  = qsup * 8 + w;         // 16-query tile in batch (0..391)
  const int q0    = qt16 * 16;
  const int wid16 = b * NT16 + qt16;

  const int start = s * kb_base + (s < kb_rem ? s : kb_rem);
  const int cnt   = kb_base + (s < kb_rem ? 1 : 0);

  const unsigned short* Qb = Qg + (size_t)b * NN * CC;
  const unsigned short* Kb = Kg + (size_t)b * NN * CC;
  const unsigned short* Vb = Vg + (size_t)b * CC * NN;

  __shared__ __align__(16) unsigned short K_lds[2][32 * 256];  // 2 x 16 KB
  __shared__ __align__(16) unsigned short V_lds[2][256 * 32];  // 2 x 16 KB
  __shared__ __align__(16) unsigned short P_lds[8][16][36];    // per-wave P

  // ---- Q B-fragments pinned (32 VGPRs) -------------------------------
  s8v qf[8];
#pragma unroll
  for (int ks = 0; ks < 8; ++ks)
    qf[ks] = *(const s8v*)(Qb + (size_t)(q0 + l15) * CC + ks * 32 + g * 8);

  f4v ot[16];
  const f4v fz = {0.f, 0.f, 0.f, 0.f};
#pragma unroll
  for (int mt = 0; mt < 16; ++mt) ot[mt] = fz;

  float lsum = 0.f;

  // ---- async stage of one 32-key tile (K by waves 0-3, V by 4-7) -----
  auto stage = [&](int buf, int kb32) {
    const int kb = kb32 * 32;
#pragma unroll
    for (int i = 0; i < 4; ++i) {
      if (w < 4) {
        int chunk = w * 256 + i * 64 + lane;           // 0..1023
        int r = chunk >> 5, cc = chunk & 31;
        const unsigned short* gp =
            Kb + (size_t)(kb + r) * CC + ((cc ^ (r & 15)) << 3);
        __builtin_amdgcn_global_load_lds(
            (const __attribute__((address_space(1))) unsigned int*)gp,
            (__attribute__((address_space(3))) unsigned int*)(&K_lds[buf][chunk * 8]),
            16, 0, 0);
      } else {
        int vc = (w - 4) * 256 + i * 64 + lane;        // 0..1023
        int ch = vc >> 2, cc = vc & 3;
        const unsigned short* gp =
            Vb + (size_t)ch * NN + kb + ((cc ^ ((ch >> 1) & 3)) << 3);
        __builtin_amdgcn_global_load_lds(
            (const __attribute__((address_space(1))) unsigned int*)gp,
            (__attribute__((address_space(3))) unsigned int*)(&V_lds[buf][vc * 8]),
            16, 0, 0);
      }
    }
  };

  stage(0, start);
  int cur = 0;

  for (int ib = 0; ib < cnt; ++ib) {
    __syncthreads();                       // buf[cur] staged; prev compute done
    if (ib + 1 < cnt) stage(cur ^ 1, start + ib + 1);   // prefetch next

    const unsigned short* Kl = &K_lds[cur][0];
    const unsigned short* Vl = &V_lds[cur][0];

    // ---- S^T = K @ Q^T (32 keys x 16 queries; Q pre-scaled) ----------
    f4v st[2];
    st[0] = fz; st[1] = fz;
#pragma unroll
    for (int ks = 0; ks < 8; ++ks) {
      const int co = ((ks * 4 + g) ^ l15) << 3;        // swizzled 16B chunk
#pragma unroll
      for (int kt = 0; kt < 2; ++kt) {
        s8v ka = *(const s8v*)(Kl + (kt * 16 + l15) * 256 + co);
        st[kt] = __builtin_amdgcn_mfma_f32_16x16x32_bf16(ka, qf[ks], st[kt], 0, 0, 0);
      }
    }

    // ---- P = exp2(S), accumulate l, pack to per-wave LDS -------------
#pragma unroll
    for (int kt = 0; kt < 2; ++kt) {
      float p0 = __builtin_amdgcn_exp2f(st[kt][0]);
      float p1 = __builtin_amdgcn_exp2f(st[kt][1]);
      float p2 = __builtin_amdgcn_exp2f(st[kt][2]);
      float p3 = __builtin_amdgcn_exp2f(st[kt][3]);
      lsum += (p0 + p1) + (p2 + p3);
      ushort4 pk;
      pk.x = f2bf(p0); pk.y = f2bf(p1); pk.z = f2bf(p2); pk.w = f2bf(p3);
      *(ushort4*)(&P_lds[w][l15][kt * 16 + 4 * g]) = pk;
    }

    // ---- O^T += V^T @ P^T (within-wave P; compiler orders lgkmcnt) ---
    s8v pb = *(const s8v*)(&P_lds[w][l15][g * 8]);
    const int vo = (g ^ ((l15 >> 1) & 3)) << 3;        // swizzled 16B chunk
#pragma unroll
    for (int mt = 0; mt < 16; ++mt) {
      s8v va = *(const s8v*)(Vl + (mt * 16 + l15) * 32 + vo);
      ot[mt] = __builtin_amdgcn_mfma_f32_16x16x32_bf16(va, pb, ot[mt], 0, 0, 0);
    }

    cur ^= 1;
  }

  // ---- reduce l across the 4 g-groups --------------------------------
  lsum += __shfl_xor(lsum, 16);
  lsum += __shfl_xor(lsum, 32);

  // ---- nontemporal bf16 fragment-native partial dump -----------------
  unsigned short* Ob = Opart + (size_t)(wid16 * split + s) * 4096;
#pragma unroll
  for (int mt = 0; mt < 16; ++mt) {
    us4v o4;
    o4.x = f2bf(ot[mt][0]); o4.y = f2bf(ot[mt][1]);
    o4.z = f2bf(ot[mt][2]); o4.w = f2bf(ot[mt][3]);
    __builtin_nontemporal_store(o4, (us4v*)(Ob + mt * 256 + lane * 4));
  }

  if (lane < 16)
    ml[(size_t)(wid16 * split + s) * 16 + lane] = lsum;
}

// ---------------------------------------------------------------------------
// Merge v2: block = 2 adjacent 16-q tiles (32 n x 256 c).
// Phase 1: read Opart fragment-native (dense 8B/lane), sum over splits,
//          normalize, deposit fp32 into lds_o[c][n] (pad 33).
// Phase 2: fully-coalesced out = lds_o + x (128B line segments).
// ---------------------------------------------------------------------------
__global__ __launch_bounds__(256) void merge_kernel(
    const unsigned short* __restrict__ Opart,
    const float* __restrict__ ml,
    const float* __restrict__ x,
    float* __restrict__ out,
    int split)
{
  const int wid32 = blockIdx.x;             // 0..391
  const int b  = wid32 / (NT16 / 2);
  const int pi = wid32 % (NT16 / 2);
  const int n0 = pi * 32;
  const int tid = threadIdx.x;
  const int w = tid >> 6;
  const int lane = tid & 63;
  const int l15 = lane & 15, g = lane >> 4;

  __shared__ float lds_o[256][33];          // 33.8 KB

#pragma unroll
  for (int t = 0; t < 2; ++t) {
    const int wid16 = b * NT16 + pi * 2 + t;
    float L = 0.f;
#pragma unroll
    for (int s = 0; s < 8; ++s)
      if (s < split)
        L += ml[(size_t)(wid16 * split + s) * 16 + l15];
    const float invL = 1.f / L;

#pragma unroll
    for (int j = 0; j < 4; ++j) {
      int mt = j * 4 + w;
      float a0 = 0.f, a1 = 0.f, a2 = 0.f, a3 = 0.f;
#pragma unroll
      for (int s = 0; s < 8; ++s)
        if (s < split) {
          const us4v* Op4 = (const us4v*)(Opart + (size_t)(wid16 * split + s) * 4096);
          us4v o4 = __builtin_nontemporal_load(Op4 + mt * 64 + lane);
          a0 += bf2f(o4.x); a1 += bf2f(o4.y);
          a2 += bf2f(o4.z); a3 += bf2f(o4.w);
        }
      int c = mt * 16 + g * 4;
      int nl = t * 16 + l15;
      lds_o[c + 0][nl] = a0 * invL;
      lds_o[c + 1][nl] = a1 * invL;
      lds_o[c + 2][nl] = a2 * invL;
      lds_o[c + 3][nl] = a3 * invL;
    }
  }
  __syncthreads();

  const size_t base = (size_t)b * CC * NN + n0;
  const int n = tid & 31;
  const int c0 = tid >> 5;                  // 0..7
#pragma unroll
  for (int cg = 0; cg < 32; ++cg) {
    int c = cg * 8 + c0;
    size_t idx = base + (size_t)c * NN + n;
    out[idx] = lds_o[c][n] + x[idx];
  }
}

extern "C" void kernel_launch(void* const* d_in, const int* in_sizes, int n_in,
                              void* d_out, int out_size, void* d_ws, size_t ws_size,
                              hipStream_t stream) {
  const float* x   = (const float*)d_in[0];
  const float* ctx = (const float*)d_in[1];
  const float* wq  = (const float*)d_in[2];
  const float* bq  = (const float*)d_in[3];
  const float* wk  = (const float*)d_in[4];
  const float* bk  = (const float*)d_in[5];
  const float* wv  = (const float*)d_in[6];
  const float* bv  = (const float*)d_in[7];
  float* out = (float*)d_out;

  const size_t sz = (size_t)BB * NN * CC;
  unsigned short* Wb = (unsigned short*)d_ws;        // 384 KB
  unsigned short* Q  = Wb + 3 * 65536;
  unsigned short* K  = Q + sz;
  unsigned short* V  = K + sz;
  const size_t fixedB = 3 * 65536 * 2 + 3 * sz * 2;  // 19.66 MB

  // split=5 -> 490 blocks = one full resident round (2 blocks/CU x 256 CU)
  int split = 1;
  const int cands[3] = {5, 2, 1};
  for (int i = 0; i < 3; ++i) {
    size_t need = fixedB + (size_t)cands[i] * (BB * NT16) *
                  (4096 * sizeof(unsigned short) + 16 * sizeof(float));
    if (ws_size >= need) { split = cands[i]; break; }
  }
  unsigned short* Opart = (unsigned short*)((char*)d_ws + fixedB);
  float* ml = (float*)(Opart + (size_t)split * (BB * NT16) * 4096);
  const int kb_base = NKB32 / split, kb_rem = NKB32 % split;

  wcvt_kernel<<<dim3(192), dim3(256), 0, stream>>>(wq, wk, wv, Wb);
  proj_kernel<<<dim3(NN / 32, BB, 3), dim3(256), 0, stream>>>(
      x, ctx, Wb, bq, bk, bv, Q, K, V);
  attn_kernel<<<dim3(98 * split), dim3(512), 0, stream>>>(
      Q, K, V, Opart, ml, split, kb_base, kb_rem);
  merge_kernel<<<dim3(BB * NT16 / 2), dim3(256), 0, stream>>>(
      Opart, ml, x, out, split);
}

// Round 11
// 258.257 us; speedup vs baseline: 1.1376x; 1.1376x over previous
//
#include <hip/hip_runtime.h>
#include <hip/hip_bf16.h>
#include <math.h>

#define BB 2
#define CC 256
#define NN 6272      // 8*28*28
#define NT16 392     // 16-query tiles per batch
#define NKB32 196    // 32-key tiles per batch
#define SCL 0.09016844005f   // log2(e)/sqrt(256)  (folded into Q at projection)

typedef __attribute__((ext_vector_type(8))) short s8v;   // 8 bf16 (4 VGPRs)
typedef __attribute__((ext_vector_type(4))) float f4v;   // MFMA acc / 16B vec
typedef __attribute__((ext_vector_type(4))) unsigned short us4v;  // 4 bf16

__device__ inline unsigned short f2bf(float f) {
  unsigned u = __builtin_bit_cast(unsigned, f);
  u += 0x7fffu + ((u >> 16) & 1u);     // RNE
  return (unsigned short)(u >> 16);
}

__device__ inline float bf2f(unsigned short h) {
  unsigned u = (unsigned)h << 16;
  return __builtin_bit_cast(float, u);
}

// ---------------------------------------------------------------------------
// fp32 weights -> bf16 (once per launch)
// ---------------------------------------------------------------------------
__global__ __launch_bounds__(256) void wcvt_kernel(
    const float* __restrict__ wq, const float* __restrict__ wk,
    const float* __restrict__ wv, unsigned short* __restrict__ Wb)
{
  int i = (blockIdx.x * 256 + threadIdx.x) * 4;   // grid 192 -> i < 196608
  const float* src = (i < 65536) ? wq : (i < 131072 ? wk : wv);
  int off = i & 65535;
  float4 v = *(const float4*)(src + off);
  ushort4 o;
  o.x = f2bf(v.x); o.y = f2bf(v.y); o.z = f2bf(v.z); o.w = f2bf(v.w);
  *(ushort4*)(Wb + i) = o;
}

// ---------------------------------------------------------------------------
// MFMA projection
// p=0: Q*SCL -> [B][N][C]   p=1: K -> [B][N][C]   p=2: V -> [B][C][N]
// ---------------------------------------------------------------------------
__global__ __launch_bounds__(256) void proj_kernel(
    const float* __restrict__ x, const float* __restrict__ ctx,
    const unsigned short* __restrict__ Wb,
    const float* __restrict__ bq, const float* __restrict__ bk,
    const float* __restrict__ bv,
    unsigned short* __restrict__ Q, unsigned short* __restrict__ Kk,
    unsigned short* __restrict__ V)
{
  const int p = blockIdx.z, b = blockIdx.y;
  const int n0 = blockIdx.x * 32;
  const int tid = threadIdx.x;
  const float* in = (p == 0 ? x : ctx) + (size_t)b * CC * NN;
  const unsigned short* W = Wb + (size_t)p * 65536;
  const float* bias = (p == 0 ? bq : (p == 1 ? bk : bv));

  __shared__ __align__(16) unsigned short lds[32][264];   // [n][c]
  for (int it = tid; it < 2048; it += 256) {
    int c  = it >> 3;
    int n4 = (it & 7) << 2;
    float4 v = *(const float4*)(in + (size_t)c * NN + n0 + n4);
    lds[n4 + 0][c] = f2bf(v.x);
    lds[n4 + 1][c] = f2bf(v.y);
    lds[n4 + 2][c] = f2bf(v.z);
    lds[n4 + 3][c] = f2bf(v.w);
  }
  __syncthreads();

  const int lane = tid & 63, l15 = lane & 15, g = lane >> 4;
  const int obase = (tid >> 6) * 64;

  f4v acc[4][2];
#pragma unroll
  for (int mt = 0; mt < 4; ++mt) {
    float4 b4 = *(const float4*)(bias + obase + mt * 16 + g * 4);
    f4v bi = {b4.x, b4.y, b4.z, b4.w};
    acc[mt][0] = bi; acc[mt][1] = bi;
  }

#pragma unroll
  for (int ks = 0; ks < 8; ++ks) {
    s8v bf0 = *(const s8v*)(&lds[l15][ks * 32 + g * 8]);
    s8v bf1 = *(const s8v*)(&lds[16 + l15][ks * 32 + g * 8]);
#pragma unroll
    for (int mt = 0; mt < 4; ++mt) {
      s8v wa = *(const s8v*)(W + (size_t)(obase + mt * 16 + l15) * CC + ks * 32 + g * 8);
      acc[mt][0] = __builtin_amdgcn_mfma_f32_16x16x32_bf16(wa, bf0, acc[mt][0], 0, 0, 0);
      acc[mt][1] = __builtin_amdgcn_mfma_f32_16x16x32_bf16(wa, bf1, acc[mt][1], 0, 0, 0);
    }
  }

  if (p == 0) {
#pragma unroll
    for (int mt = 0; mt < 4; ++mt)
#pragma unroll
      for (int qq = 0; qq < 2; ++qq)
#pragma unroll
        for (int r = 0; r < 4; ++r)
          acc[mt][qq][r] *= SCL;
  }

  if (p < 2) {
    unsigned short* dst = (p == 0 ? Q : Kk) + (size_t)b * NN * CC;
#pragma unroll
    for (int mt = 0; mt < 4; ++mt)
#pragma unroll
      for (int qq = 0; qq < 2; ++qq) {
        ushort4 pk;
        pk.x = f2bf(acc[mt][qq][0]); pk.y = f2bf(acc[mt][qq][1]);
        pk.z = f2bf(acc[mt][qq][2]); pk.w = f2bf(acc[mt][qq][3]);
        *(ushort4*)(dst + (size_t)(n0 + qq * 16 + l15) * CC + obase + mt * 16 + g * 4) = pk;
      }
  } else {
    unsigned short* dstb = V + (size_t)b * CC * NN;
#pragma unroll
    for (int mt = 0; mt < 4; ++mt)
#pragma unroll
      for (int qq = 0; qq < 2; ++qq)
#pragma unroll
        for (int r = 0; r < 4; ++r)
          dstb[(size_t)(obase + mt * 16 + g * 4 + r) * NN + n0 + qq * 16 + l15] =
              f2bf(acc[mt][qq][r]);
  }
}

// ---------------------------------------------------------------------------
// Flash attention (no-max exp2). 256-thread blocks = 4 waves, 16 queries/wave
// (64 q/block). Same total waves as the 512-thread variant but 4 blocks/CU =
// 4 INDEPENDENT barrier domains per CU: while one block drains its staging
// vmcnt at __syncthreads, the other three issue MFMA. LDS 37.4 KB/block.
// Contiguous split-K (split=5 -> 980 blocks = one full resident round).
// K/V double-buffered via global_load_lds (16B), global-side XOR swizzles
// keep all fragment ds_read_b128 conflict-free. Partials bf16.
// ---------------------------------------------------------------------------
__global__ __launch_bounds__(256, 4) void attn_kernel(
    const unsigned short* __restrict__ Qg,
    const unsigned short* __restrict__ Kg,
    const unsigned short* __restrict__ Vg,
    unsigned short* __restrict__ Opart,  // [wid16*split+s][4096] bf16
    float* __restrict__ ml,              // [wid16*split+s][16]
    int split, int kb_base, int kb_rem)
{
  const int s     = blockIdx.x % split;
  const int stile = blockIdx.x / split;   // 0..195
  const int b     = stile / 98;
  const int qsup  = stile % 98;
  const int tid   = threadIdx.x;
  const int w     = tid >> 6;             // 0..3
  const int lane  = tid & 63;
  const int l15 = lane & 15, g = lane >> 4;
  const int qt16  = qsup * 4 + w;         // 16-query tile in batch (0..391)
  const int q0    = qt16 * 16;
  const int wid16 = b * NT16 + qt16;

  const int start = s * kb_base + (s < kb_rem ? s : kb_rem);
  const int cnt   = kb_base + (s < kb_rem ? 1 : 0);

  const unsigned short* Qb = Qg + (size_t)b * NN * CC;
  const unsigned short* Kb = Kg + (size_t)b * NN * CC;
  const unsigned short* Vb = Vg + (size_t)b * CC * NN;

  __shared__ __align__(16) unsigned short K_lds[2][32 * 256];  // 2 x 16 KB
  __shared__ __align__(16) unsigned short V_lds[2][256 * 32];  // 2 x 16 KB
  __shared__ __align__(16) unsigned short P_lds[4][16][36];    // per-wave P

  // ---- Q B-fragments pinned (32 VGPRs) -------------------------------
  s8v qf[8];
#pragma unroll
  for (int ks = 0; ks < 8; ++ks)
    qf[ks] = *(const s8v*)(Qb + (size_t)(q0 + l15) * CC + ks * 32 + g * 8);

  f4v ot[16];
  const f4v fz = {0.f, 0.f, 0.f, 0.f};
#pragma unroll
  for (int mt = 0; mt < 16; ++mt) ot[mt] = fz;

  float lsum = 0.f;

  // ---- async stage of one 32-key tile (K waves 0-1, V waves 2-3) -----
  auto stage = [&](int buf, int kb32) {
    const int kb = kb32 * 32;
#pragma unroll
    for (int i = 0; i < 8; ++i) {
      int chunk = w * 512 + i * 64 + lane;             // 0..2047 (16B units)
      if (chunk < 1024) {                              // K part
        int r = chunk >> 5, cc = chunk & 31;
        const unsigned short* gp =
            Kb + (size_t)(kb + r) * CC + ((cc ^ (r & 15)) << 3);
        __builtin_amdgcn_global_load_lds(
            (const __attribute__((address_space(1))) unsigned int*)gp,
            (__attribute__((address_space(3))) unsigned int*)(&K_lds[buf][chunk * 8]),
            16, 0, 0);
      } else {                                         // V part
        int vc = chunk - 1024;
        int ch = vc >> 2, cc = vc & 3;
        const unsigned short* gp =
            Vb + (size_t)ch * NN + kb + ((cc ^ ((ch >> 1) & 3)) << 3);
        __builtin_amdgcn_global_load_lds(
            (const __attribute__((address_space(1))) unsigned int*)gp,
            (__attribute__((address_space(3))) unsigned int*)(&V_lds[buf][vc * 8]),
            16, 0, 0);
      }
    }
  };

  stage(0, start);
  int cur = 0;

  for (int ib = 0; ib < cnt; ++ib) {
    __syncthreads();                       // buf[cur] staged; prev compute done
    if (ib + 1 < cnt) stage(cur ^ 1, start + ib + 1);   // prefetch next

    const unsigned short* Kl = &K_lds[cur][0];
    const unsigned short* Vl = &V_lds[cur][0];

    // ---- S^T = K @ Q^T (32 keys x 16 queries; Q pre-scaled) ----------
    f4v st[2];
    st[0] = fz; st[1] = fz;
#pragma unroll
    for (int ks = 0; ks < 8; ++ks) {
      const int co = ((ks * 4 + g) ^ l15) << 3;        // swizzled 16B chunk
#pragma unroll
      for (int kt = 0; kt < 2; ++kt) {
        s8v ka = *(const s8v*)(Kl + (kt * 16 + l15) * 256 + co);
        st[kt] = __builtin_amdgcn_mfma_f32_16x16x32_bf16(ka, qf[ks], st[kt], 0, 0, 0);
      }
    }

    // ---- P = exp2(S), accumulate l, pack to per-wave LDS -------------
#pragma unroll
    for (int kt = 0; kt < 2; ++kt) {
      float p0 = __builtin_amdgcn_exp2f(st[kt][0]);
      float p1 = __builtin_amdgcn_exp2f(st[kt][1]);
      float p2 = __builtin_amdgcn_exp2f(st[kt][2]);
      float p3 = __builtin_amdgcn_exp2f(st[kt][3]);
      lsum += (p0 + p1) + (p2 + p3);
      ushort4 pk;
      pk.x = f2bf(p0); pk.y = f2bf(p1); pk.z = f2bf(p2); pk.w = f2bf(p3);
      *(ushort4*)(&P_lds[w][l15][kt * 16 + 4 * g]) = pk;
    }

    // ---- O^T += V^T @ P^T (within-wave P; compiler orders lgkmcnt) ---
    s8v pb = *(const s8v*)(&P_lds[w][l15][g * 8]);
    const int vo = (g ^ ((l15 >> 1) & 3)) << 3;        // swizzled 16B chunk
#pragma unroll
    for (int mt = 0; mt < 16; ++mt) {
      s8v va = *(const s8v*)(Vl + (mt * 16 + l15) * 32 + vo);
      ot[mt] = __builtin_amdgcn_mfma_f32_16x16x32_bf16(va, pb, ot[mt], 0, 0, 0);
    }

    cur ^= 1;
  }

  // ---- reduce l across the 4 g-groups --------------------------------
  lsum += __shfl_xor(lsum, 16);
  lsum += __shfl_xor(lsum, 32);

  // ---- nontemporal bf16 fragment-native partial dump -----------------
  unsigned short* Ob = Opart + (size_t)(wid16 * split + s) * 4096;
#pragma unroll
  for (int mt = 0; mt < 16; ++mt) {
    us4v o4;
    o4.x = f2bf(ot[mt][0]); o4.y = f2bf(ot[mt][1]);
    o4.z = f2bf(ot[mt][2]); o4.w = f2bf(ot[mt][3]);
    __builtin_nontemporal_store(o4, (us4v*)(Ob + mt * 256 + lane * 4));
  }

  if (lane < 16)
    ml[(size_t)(wid16 * split + s) * 16 + lane] = lsum;
}

// ---------------------------------------------------------------------------
// Merge v2: block = 2 adjacent 16-q tiles (32 n x 256 c).
// Phase 1: read Opart fragment-native (dense 8B/lane), sum over splits,
//          normalize, deposit fp32 into lds_o[c][n] (pad 33).
// Phase 2: fully-coalesced out = lds_o + x (128B line segments).
// ---------------------------------------------------------------------------
__global__ __launch_bounds__(256) void merge_kernel(
    const unsigned short* __restrict__ Opart,
    const float* __restrict__ ml,
    const float* __restrict__ x,
    float* __restrict__ out,
    int split)
{
  const int wid32 = blockIdx.x;             // 0..391
  const int b  = wid32 / (NT16 / 2);
  const int pi = wid32 % (NT16 / 2);
  const int n0 = pi * 32;
  const int tid = threadIdx.x;
  const int w = tid >> 6;
  const int lane = tid & 63;
  const int l15 = lane & 15, g = lane >> 4;

  __shared__ float lds_o[256][33];          // 33.8 KB

#pragma unroll
  for (int t = 0; t < 2; ++t) {
    const int wid16 = b * NT16 + pi * 2 + t;
    float L = 0.f;
#pragma unroll
    for (int s = 0; s < 8; ++s)
      if (s < split)
        L += ml[(size_t)(wid16 * split + s) * 16 + l15];
    const float invL = 1.f / L;

#pragma unroll
    for (int j = 0; j < 4; ++j) {
      int mt = j * 4 + w;
      float a0 = 0.f, a1 = 0.f, a2 = 0.f, a3 = 0.f;
#pragma unroll
      for (int s = 0; s < 8; ++s)
        if (s < split) {
          const us4v* Op4 = (const us4v*)(Opart + (size_t)(wid16 * split + s) * 4096);
          us4v o4 = __builtin_nontemporal_load(Op4 + mt * 64 + lane);
          a0 += bf2f(o4.x); a1 += bf2f(o4.y);
          a2 += bf2f(o4.z); a3 += bf2f(o4.w);
        }
      int c = mt * 16 + g * 4;
      int nl = t * 16 + l15;
      lds_o[c + 0][nl] = a0 * invL;
      lds_o[c + 1][nl] = a1 * invL;
      lds_o[c + 2][nl] = a2 * invL;
      lds_o[c + 3][nl] = a3 * invL;
    }
  }
  __syncthreads();

  const size_t base = (size_t)b * CC * NN + n0;
  const int n = tid & 31;
  const int c0 = tid >> 5;                  // 0..7
#pragma unroll
  for (int cg = 0; cg < 32; ++cg) {
    int c = cg * 8 + c0;
    size_t idx = base + (size_t)c * NN + n;
    out[idx] = lds_o[c][n] + x[idx];
  }
}

extern "C" void kernel_launch(void* const* d_in, const int* in_sizes, int n_in,
                              void* d_out, int out_size, void* d_ws, size_t ws_size,
                              hipStream_t stream) {
  const float* x   = (const float*)d_in[0];
  const float* ctx = (const float*)d_in[1];
  const float* wq  = (const float*)d_in[2];
  const float* bq  = (const float*)d_in[3];
  const float* wk  = (const float*)d_in[4];
  const float* bk  = (const float*)d_in[5];
  const float* wv  = (const float*)d_in[6];
  const float* bv  = (const float*)d_in[7];
  float* out = (float*)d_out;

  const size_t sz = (size_t)BB * NN * CC;
  unsigned short* Wb = (unsigned short*)d_ws;        // 384 KB
  unsigned short* Q  = Wb + 3 * 65536;
  unsigned short* K  = Q + sz;
  unsigned short* V  = K + sz;
  const size_t fixedB = 3 * 65536 * 2 + 3 * sz * 2;  // 19.66 MB

  // split=5 -> 980 blocks = one full resident round (4 blocks/CU x 256 CU)
  int split = 1;
  const int cands[3] = {5, 2, 1};
  for (int i = 0; i < 3; ++i) {
    size_t need = fixedB + (size_t)cands[i] * (BB * NT16) *
                  (4096 * sizeof(unsigned short) + 16 * sizeof(float));
    if (ws_size >= need) { split = cands[i]; break; }
  }
  unsigned short* Opart = (unsigned short*)((char*)d_ws + fixedB);
  float* ml = (float*)(Opart + (size_t)split * (BB * NT16) * 4096);
  const int kb_base = NKB32 / split, kb_rem = NKB32 % split;

  wcvt_kernel<<<dim3(192), dim3(256), 0, stream>>>(wq, wk, wv, Wb);
  proj_kernel<<<dim3(NN / 32, BB, 3), dim3(256), 0, stream>>>(
      x, ctx, Wb, bq, bk, bv, Q, K, V);
  attn_kernel<<<dim3(196 * split), dim3(256), 0, stream>>>(
      Q, K, V, Opart, ml, split, kb_base, kb_rem);
  merge_kernel<<<dim3(BB * NT16 / 2), dim3(256), 0, stream>>>(
      Opart, ml, x, out, split);
}